// Round 11
// baseline (224.683 us; speedup 1.0000x reference)
//
#include <hip/hip_runtime.h>

#define B_ 1024
#define D_ 512
#define T_ 36
#define NT_ 64
#define DS_ 32
#define EPS_ 1e-5f

typedef float f32x4 __attribute__((ext_vector_type(4)));
typedef __bf16 bf16x8 __attribute__((ext_vector_type(8)));
typedef unsigned short u16x8 __attribute__((ext_vector_type(8)));
typedef unsigned short u16x4 __attribute__((ext_vector_type(4)));

#define DEVI static __device__ __forceinline__
#define MFMA16 __builtin_amdgcn_mfma_f32_16x16x32_bf16

DEVI unsigned short f2bf(float f) { return __builtin_bit_cast(unsigned short, (__bf16)f); }
DEVI float bf2f(unsigned short h) { return (float)__builtin_bit_cast(__bf16, h); }

// XOR-swizzled byte offset inside a [48 rows][1024B] transposed image (T2)
DEVI unsigned swz(int row, int col) {   // col in ushort elements (0..511)
    return (unsigned)(row * 1024 + ((2 * col) ^ ((row & 7) << 4)));
}

// ---- 2-acc K=512 tile: A row from global, B from swz image ----
DEVI f32x4 tile16_gl(const unsigned short* __restrict__ Arow, const char* img, int brow, int l4)
{
    f32x4 acc0 = {0.f,0.f,0.f,0.f}, acc1 = {0.f,0.f,0.f,0.f};
    #pragma unroll
    for (int ks = 0; ks < 16; ks += 2) {
        int ka = ks * 32 + l4 * 8, kb = ka + 32;
        acc0 = MFMA16(*(const bf16x8*)(Arow + ka), *(const bf16x8*)(img + swz(brow, ka)), acc0, 0, 0, 0);
        acc1 = MFMA16(*(const bf16x8*)(Arow + kb), *(const bf16x8*)(img + swz(brow, kb)), acc1, 0, 0, 0);
    }
    return acc0 + acc1;
}

// ---- same, A also from a swizzled LDS image ----
DEVI f32x4 tile16_ll(const char* imgA, int arow, const char* imgB, int brow, int l4)
{
    f32x4 acc0 = {0.f,0.f,0.f,0.f}, acc1 = {0.f,0.f,0.f,0.f};
    #pragma unroll
    for (int ks = 0; ks < 16; ks += 2) {
        int ka = ks * 32 + l4 * 8, kb = ka + 32;
        acc0 = MFMA16(*(const bf16x8*)(imgA + swz(arow, ka)), *(const bf16x8*)(imgB + swz(brow, ka)), acc0, 0, 0, 0);
        acc1 = MFMA16(*(const bf16x8*)(imgA + swz(arow, kb)), *(const bf16x8*)(imgB + swz(brow, kb)), acc1, 0, 0, 0);
    }
    return acc0 + acc1;
}

// ---- K1 LDS layout (r5) ----
#define OFF_XST 49152    // xsT [48][1024B] swz ; h image overlay happens at YST (region 0)
#define OFF_SC  98304    // sc f32 [64][42] ; red overlay
#define OFF_A1  109056   // a1  u16 [64][72]
#define OFF_A1T 118272   // a1t u16 [48][72]
#define OFF_A2  125184   // a2  u16 [48][72]
#define OFF_GT  132096   // gt  u16 [48][72]
#define OFF_W   139008   // W   u16 [48][72]
#define K1_LDS  145920

// ---- K0: prepack tok bf16 [64][512], tokT bf16 [512][64], block-diag wd bf16 [32][512] ----
__global__ __launch_bounds__(512)
void k0_prepack(const float* __restrict__ tok, const float* __restrict__ wd,
                unsigned short* __restrict__ tokbf, unsigned short* __restrict__ tokT,
                unsigned short* __restrict__ wdd)
{
    int i = blockIdx.x * 512 + threadIdx.x;
    if (i < 32768) {
        tokbf[i] = f2bf(tok[i]);
    } else if (i < 65536) {
        int j = i - 32768; int d = j >> 6, t = j & 63;
        tokT[j] = f2bf(tok[t * 512 + d]);
    } else if (i < 81920) {
        int j = i - 65536; int o = j >> 9, dd = j & 511;
        wdd[j] = ((dd >> 7) == (o >> 3)) ? f2bf(wd[o * 128 + (dd & 127)]) : (unsigned short)0;
    }
}

// stage one transpose unit u (0..575) of src into image dst
DEVI void stage_unit(const float* __restrict__ src, char* __restrict__ dst, int u)
{
    int dblk = u / 9, s4 = u - dblk * 9;
    int s0 = s4 * 4;
    const float* bp = src + dblk * 8 * T_ + s0;
    u16x8 u0, u1, u2, u3;
    #pragma unroll
    for (int r = 0; r < 8; ++r) {
        f32x4 v = *(const f32x4*)(bp + r * T_);
        u0[r] = f2bf(v[0]); u1[r] = f2bf(v[1]);
        u2[r] = f2bf(v[2]); u3[r] = f2bf(v[3]);
    }
    *(u16x8*)(dst + swz(s0 + 0, dblk * 8)) = u0;
    *(u16x8*)(dst + swz(s0 + 1, dblk * 8)) = u1;
    *(u16x8*)(dst + swz(s0 + 2, dblk * 8)) = u2;
    *(u16x8*)(dst + swz(s0 + 3, dblk * 8)) = u3;
}

// =================== K1: fused attention + LN + downconv (W-algebra, phase-overlapped) ===================
__global__ __launch_bounds__(1024, 4)
void k1_fused(const float* __restrict__ x, const float* __restrict__ y,
              const unsigned short* __restrict__ tokbf, const unsigned short* __restrict__ tokT,
              const float* __restrict__ gav_p, const unsigned short* __restrict__ wdd,
              const float* __restrict__ lnbg, const float* __restrict__ lnbb,
              float* __restrict__ z_pre)
{
    extern __shared__ char lds[];
    float* sc = (float*)(lds + OFF_SC);
    unsigned short* a1  = (unsigned short*)(lds + OFF_A1);
    unsigned short* a1t = (unsigned short*)(lds + OFF_A1T);
    unsigned short* a2  = (unsigned short*)(lds + OFF_A2);
    unsigned short* gt  = (unsigned short*)(lds + OFF_GT);
    unsigned short* wb  = (unsigned short*)(lds + OFF_W);

    const int b    = blockIdx.x;
    const int tid  = threadIdx.x;
    const int lane = tid & 63;
    const int w    = tid >> 6;   // 0..15
    const int l15  = lane & 15;
    const int l4   = lane >> 4;  // 0..3

    const float* yb = y + b * (D_ * T_);
    const float* xb = x + b * (D_ * T_);

    // ---- P0: stage ysT (threads 0..575) || zero pads (threads 576..1023) ----
    if (tid < 576) {
        stage_unit(yb, lds, tid);
    } else {
        int z = tid - 576;
        unsigned* z1 = (unsigned*)(lds + 36 * 1024);
        for (int i = z; i < 3072; i += 448) z1[i] = 0u;
        unsigned* z2 = (unsigned*)(lds + OFF_XST + 36 * 1024);
        for (int i = z; i < 3072; i += 448) z2[i] = 0u;
        unsigned* z3 = (unsigned*)(lds + OFF_A1);   // a1..W contiguous: 36,864 B
        for (int i = z; i < 9216; i += 448) z3[i] = 0u;
    }
    __syncthreads();

    // ---- P1a: G1 (S1 = tok@y, 12 tiles, waves 0..11) || stage xsT (waves 12..15) ----
    if (w < 12) {
        int mt = w / 3, nt = w % 3;
        int trow = mt * 16 + l15, srow = nt * 16 + l15;
        f32x4 acc = tile16_gl(tokbf + trow * 512, lds, srow, l4);
        if (srow < T_) {
            #pragma unroll
            for (int j = 0; j < 4; ++j)
                sc[(mt * 16 + l4 * 4 + j) * 42 + srow] = acc[j];
        }
    } else {
        for (int u = tid - 768; u < 576; u += 256)
            stage_unit(xb, lds + OFF_XST, u);
    }
    __syncthreads();

    // ---- P1b: GramT (gt[sx][sy] = x^T y, 9 tiles) ----
    if (w < 9) {
        int mt = w / 3, nt = w % 3;
        int arow = mt * 16 + l15, brow = nt * 16 + l15;
        f32x4 acc = tile16_ll(lds + OFF_XST, arow, lds, brow, l4);
        #pragma unroll
        for (int j = 0; j < 4; ++j) {
            int gr = mt * 16 + l4 * 4 + j;
            if (gr < T_) gt[gr * 72 + brow] = f2bf(acc[j]);
        }
    }
    __syncthreads();

    // ---- sm1: softmax over s per t -> a1 [t][s], a1t [s][t] ; prefetch P6's y rows ----
    {
        int t = tid >> 4, l16 = tid & 15;
        const float* scp = sc + t * 42;
        float v0 = scp[l16];
        float v1 = scp[l16 + 16];
        float v2 = (l16 < 4) ? scp[l16 + 32] : -1e30f;
        float m = fmaxf(fmaxf(v0, v1), v2);
        #pragma unroll
        for (int off = 1; off < 16; off <<= 1) m = fmaxf(m, __shfl_xor(m, off));
        float e0 = __expf(v0 - m), e1 = __expf(v1 - m);
        float e2 = (l16 < 4) ? __expf(v2 - m) : 0.f;
        float ssum = e0 + e1 + e2;
        #pragma unroll
        for (int off = 1; off < 16; off <<= 1) ssum += __shfl_xor(ssum, off);
        float inv = 1.f / ssum;
        unsigned short h0 = f2bf(e0 * inv), h1 = f2bf(e1 * inv);
        a1[t * 72 + l16] = h0;       a1[t * 72 + l16 + 16] = h1;
        a1t[l16 * 72 + t] = h0;      a1t[(l16 + 16) * 72 + t] = h1;
        if (l16 < 4) {
            unsigned short h2 = f2bf(e2 * inv);
            a1[t * 72 + l16 + 32] = h2;
            a1t[(l16 + 32) * 72 + t] = h2;
        }
    }
    // prefetch y rows for P6 (held in registers across P3/P5)
    f32x4 py0[2], py1[2], py2[2];
    #pragma unroll
    for (int mi = 0; mi < 2; ++mi) {
        const float* yrow = yb + ((2 * w + mi) * 16 + l15) * T_;
        py0[mi] = *(const f32x4*)(yrow + l4 * 8);
        py1[mi] = *(const f32x4*)(yrow + l4 * 8 + 4);
        if (l4 == 0) py2[mi] = *(const f32x4*)(yrow + 32);
        else         py2[mi] = (f32x4){0.f, 0.f, 0.f, 0.f};
    }
    __syncthreads();

    // ---- P3: S2[t][s] = tok@x (K=512) + a1@gt^T (K=36 pad 64); 12 tiles ----
    if (w < 12) {
        int mt = w / 3, nt = w % 3;
        int trow = mt * 16 + l15, srow = nt * 16 + l15;
        bf16x8 sa0 = *(const bf16x8*)(a1 + trow * 72 + l4 * 8);
        bf16x8 sa1 = *(const bf16x8*)(a1 + trow * 72 + 32 + l4 * 8);
        bf16x8 sb0 = *(const bf16x8*)(gt + srow * 72 + l4 * 8);
        bf16x8 sb1 = *(const bf16x8*)(gt + srow * 72 + 32 + l4 * 8);
        f32x4 acc = tile16_gl(tokbf + trow * 512, lds + OFF_XST, srow, l4);
        acc = MFMA16(sa0, sb0, acc, 0, 0, 0);
        acc = MFMA16(sa1, sb1, acc, 0, 0, 0);
        if (srow < T_) {
            #pragma unroll
            for (int j = 0; j < 4; ++j)
                sc[(mt * 16 + l4 * 4 + j) * 42 + srow] = acc[j];
        }
    }
    __syncthreads();

    // ---- sm2: softmax over t per s -> a2 [s][t] ----
    if (tid < 768) {
        int s = tid >> 4, l16 = tid & 15;
        if (s < T_) {
            float v0 = sc[(l16) * 42 + s];
            float v1 = sc[(l16 + 16) * 42 + s];
            float v2 = sc[(l16 + 32) * 42 + s];
            float v3 = sc[(l16 + 48) * 42 + s];
            float m = fmaxf(fmaxf(v0, v1), fmaxf(v2, v3));
            #pragma unroll
            for (int off = 1; off < 16; off <<= 1) m = fmaxf(m, __shfl_xor(m, off));
            float e0 = __expf(v0 - m), e1 = __expf(v1 - m), e2 = __expf(v2 - m), e3 = __expf(v3 - m);
            float ssum = e0 + e1 + e2 + e3;
            #pragma unroll
            for (int off = 1; off < 16; off <<= 1) ssum += __shfl_xor(ssum, off);
            float inv = 1.f / ssum;
            a2[s * 72 + l16]      = f2bf(e0 * inv);
            a2[s * 72 + l16 + 16] = f2bf(e1 * inv);
            a2[s * 72 + l16 + 32] = f2bf(e2 * inv);
            a2[s * 72 + l16 + 48] = f2bf(e3 * inv);
        }
    }
    __syncthreads();

    // ---- P5: W[s2][s1] = a2 @ a1t^T (K=t=64, 9 tiles) ----
    if (w < 9) {
        int mt = w / 3, nt = w % 3;
        f32x4 acc = {0.f, 0.f, 0.f, 0.f};
        #pragma unroll
        for (int ks = 0; ks < 2; ++ks) {
            int k0 = ks * 32 + l4 * 8;
            acc = MFMA16(*(const bf16x8*)(a2 + (mt * 16 + l15) * 72 + k0),
                         *(const bf16x8*)(a1t + (nt * 16 + l15) * 72 + k0), acc, 0, 0, 0);
        }
        #pragma unroll
        for (int j = 0; j < 4; ++j)
            wb[(mt * 16 + l4 * 4 + j) * 72 + nt * 16 + l15] = f2bf(acc[j]);
    }
    __syncthreads();

    // ---- P6: xresT[d][s] = tokT@a2^T + y@W^T ; xc ; LN -> h image (region 0) ----
    {
        const float gav = gav_p[0];
        f32x4 acc[2][3];
        #pragma unroll
        for (int mi = 0; mi < 2; ++mi)
            #pragma unroll
            for (int n = 0; n < 3; ++n) acc[mi][n] = (f32x4){0.f, 0.f, 0.f, 0.f};

        bf16x8 aT[2][2], aY[2][2];
        #pragma unroll
        for (int mi = 0; mi < 2; ++mi) {
            int d = (2 * w + mi) * 16 + l15;
            aT[mi][0] = *(const bf16x8*)(tokT + d * 64 + l4 * 8);
            aT[mi][1] = *(const bf16x8*)(tokT + d * 64 + 32 + l4 * 8);
            bf16x8 t0, t1;
            #pragma unroll
            for (int j = 0; j < 4; ++j) {
                t0[j] = (__bf16)py0[mi][j]; t0[4 + j] = (__bf16)py1[mi][j];
                t1[j] = (__bf16)py2[mi][j]; t1[4 + j] = (__bf16)0.f;
            }
            aY[mi][0] = t0; aY[mi][1] = t1;
        }
        #pragma unroll
        for (int n = 0; n < 3; ++n) {
            int srow = n * 16 + l15;
            bf16x8 b20 = *(const bf16x8*)(a2 + srow * 72 + l4 * 8);
            bf16x8 b21 = *(const bf16x8*)(a2 + srow * 72 + 32 + l4 * 8);
            bf16x8 bw0 = *(const bf16x8*)(wb + srow * 72 + l4 * 8);
            bf16x8 bw1 = *(const bf16x8*)(wb + srow * 72 + 32 + l4 * 8);
            #pragma unroll
            for (int mi = 0; mi < 2; ++mi) {
                acc[mi][n] = MFMA16(aT[mi][0], b20, acc[mi][n], 0, 0, 0);
                acc[mi][n] = MFMA16(aT[mi][1], b21, acc[mi][n], 0, 0, 0);
                acc[mi][n] = MFMA16(aY[mi][0], bw0, acc[mi][n], 0, 0, 0);
                acc[mi][n] = MFMA16(aY[mi][1], bw1, acc[mi][n], 0, 0, 0);
            }
        }

        // xc = xs + gav*x_res ; per-s LN partials (u16x4 xc reads)
        float* red = sc;   // overlays dead sc
        float rs_[3] = {0.f, 0.f, 0.f}, rq_[3] = {0.f, 0.f, 0.f};
        #pragma unroll
        for (int mi = 0; mi < 2; ++mi) {
            int dcol = (2 * w + mi) * 16 + l4 * 4;
            #pragma unroll
            for (int n = 0; n < 3; ++n) {
                int s = n * 16 + l15;
                if (s < T_) {
                    u16x4 xv = *(const u16x4*)(lds + OFF_XST + swz(s, dcol));
                    #pragma unroll
                    for (int j = 0; j < 4; ++j) {
                        float v = bf2f(xv[j]) + gav * acc[mi][n][j];
                        acc[mi][n][j] = v;
                        rs_[n] += v; rq_[n] += v * v;
                    }
                }
            }
        }
        #pragma unroll
        for (int n = 0; n < 3; ++n) {
            rs_[n] += __shfl_xor(rs_[n], 16); rq_[n] += __shfl_xor(rq_[n], 16);
            rs_[n] += __shfl_xor(rs_[n], 32); rq_[n] += __shfl_xor(rq_[n], 32);
        }
        if (l4 == 0) {
            #pragma unroll
            for (int n = 0; n < 3; ++n) {
                int s = n * 16 + l15;
                if (s < T_) { red[s * 16 + w] = rs_[n]; red[768 + s * 16 + w] = rq_[n]; }
            }
        }
        __syncthreads();
        if (tid < T_) {
            int s = tid; float S = 0.f, Q = 0.f;
            #pragma unroll
            for (int q = 0; q < 16; ++q) { S += red[s * 16 + q]; Q += red[768 + s * 16 + q]; }
            float mu = S * (1.f / 512.f);
            float var = Q * (1.f / 512.f) - mu * mu;
            red[1536 + s] = mu; red[1584 + s] = rsqrtf(var + EPS_);
        }
        __syncthreads();

        // h (LN output) -> region 0 image (ysT dead); u16x4 writes
        #pragma unroll
        for (int mi = 0; mi < 2; ++mi) {
            int dcol = (2 * w + mi) * 16 + l4 * 4;
            f32x4 gv  = *(const f32x4*)(lnbg + dcol);
            f32x4 bv2 = *(const f32x4*)(lnbb + dcol);
            #pragma unroll
            for (int n = 0; n < 3; ++n) {
                int s = n * 16 + l15;
                if (s < T_) {
                    float mu = red[1536 + s], rsg = red[1584 + s];
                    u16x4 hv;
                    #pragma unroll
                    for (int j = 0; j < 4; ++j)
                        hv[j] = f2bf((acc[mi][n][j] - mu) * rsg * gv[j] + bv2[j]);
                    *(u16x4*)(lds + swz(s, dcol)) = hv;
                }
            }
        }
    }
    __syncthreads();

    // ---- P7: grouped down conv via MFMA: z[o][s] = wdd(blockdiag) @ h ----
    if (w < 6) {
        int mt = w / 3, nt = w % 3;
        int orow = mt * 16 + l15, srow = nt * 16 + l15;
        f32x4 acc = tile16_gl(wdd + orow * 512, lds, srow, l4);
        if (srow < T_) {
            #pragma unroll
            for (int j = 0; j < 4; ++j)
                z_pre[b * (DS_ * T_) + (mt * 16 + l4 * 4 + j) * T_ + srow] = acc[j];
        }
    }
}

// ---- K3: bn1 stats (fused two-level; one block per channel) ----
__global__ __launch_bounds__(256)
void k3_bn1(const float* __restrict__ z_pre, float* __restrict__ st1)
{
    __shared__ float rbuf[4][2];
    int o = blockIdx.x;
    int tid = threadIdx.x;
    float S = 0.f, Q = 0.f;
    for (int i = tid; i < B_ * T_; i += 256) {
        int b = i / T_, t = i - b * T_;
        float v = z_pre[b * (DS_ * T_) + o * T_ + t];
        S += v; Q += v * v;
    }
    #pragma unroll
    for (int off = 1; off < 64; off <<= 1) { S += __shfl_xor(S, off); Q += __shfl_xor(Q, off); }
    int ww = tid >> 6;
    if ((tid & 63) == 0) { rbuf[ww][0] = S; rbuf[ww][1] = Q; }
    __syncthreads();
    if (tid == 0) {
        float s2 = 0.f, q2 = 0.f;
        for (int i = 0; i < 4; ++i) { s2 += rbuf[i][0]; q2 += rbuf[i][1]; }
        float mu = s2 / 36864.f;
        float var = q2 / 36864.f - mu * mu;
        st1[o] = mu; st1[32 + o] = rsqrtf(var + EPS_);
    }
}

// ---- K4M: per-group 8x8 second-moment partials of zr = relu(bn1(z)) ----
__global__ __launch_bounds__(256)
void k4m_moments(const float* __restrict__ z_pre, const float* __restrict__ st1,
                 const float* __restrict__ g1p, const float* __restrict__ b1p,
                 float* __restrict__ m4)
{
    __shared__ float zr[32][40];
    int blk = blockIdx.x, tid = threadIdx.x;
    int c2 = tid & 7, c1 = (tid >> 3) & 7, g = tid >> 6;
    int ch1 = g * 8 + c1, ch2 = g * 8 + c2;
    float acc = 0.f, asum = 0.f;
    for (int bi = 0; bi < 8; ++bi) {
        int b = blk * 8 + bi;
        __syncthreads();
        for (int i = tid; i < DS_ * T_; i += 256) {
            int o = i / T_, t = i - o * T_;
            float v = z_pre[b * (DS_ * T_) + i];
            zr[o][t] = fmaxf(0.f, (v - st1[o]) * st1[32 + o] * g1p[o] + b1p[o]);
        }
        __syncthreads();
        for (int t = 0; t < T_; ++t) {
            float a = zr[ch1][t], b2 = zr[ch2][t];
            acc += a * b2;
            asum += a;
        }
    }
    m4[blk * 288 + tid] = acc;
    if (c1 == c2) m4[blk * 288 + 256 + g * 8 + c1] = asum;
}

// ---- K4S: reduce moments -> bn2 stats via E[o^2] = w^T M w ----
__global__ __launch_bounds__(512)
void k4s_bn2stats(const float* __restrict__ m4, const float* __restrict__ wu,
                  float* __restrict__ st2)
{
    __shared__ float M2[256], mz[32];
    int tid = threadIdx.x;
    if (tid < 256) {
        float S = 0.f;
        for (int k = 0; k < 128; ++k) S += m4[k * 288 + tid];
        M2[tid] = S * (1.f / 36864.f);
    } else if (tid < 288) {
        int j = tid - 256;
        float S = 0.f;
        for (int k = 0; k < 128; ++k) S += m4[k * 288 + 256 + j];
        mz[j] = S * (1.f / 36864.f);
    }
    __syncthreads();
    int d = tid, g = d >> 7;
    float wr[8];
    #pragma unroll
    for (int c = 0; c < 8; ++c) wr[c] = wu[d * 8 + c];
    float mu2 = 0.f;
    #pragma unroll
    for (int c = 0; c < 8; ++c) mu2 += wr[c] * mz[g * 8 + c];
    float e2 = 0.f;
    #pragma unroll
    for (int c = 0; c < 8; ++c)
        #pragma unroll
        for (int c2 = 0; c2 < 8; ++c2)
            e2 += wr[c] * wr[c2] * M2[g * 64 + c * 8 + c2];
    st2[d] = mu2;
    st2[512 + d] = rsqrtf(e2 - mu2 * mu2 + EPS_);
}

// ---- K5: up conv + bn2 + LN(lnp) + gate -> out ----
#define K5_LDS 47888
__global__ __launch_bounds__(512, 6)
void k5_final(const float* __restrict__ z_pre, const float* __restrict__ st1,
              const float* __restrict__ g1p, const float* __restrict__ b1p,
              const float* __restrict__ wu, const float* __restrict__ st2,
              const float* __restrict__ g2p, const float* __restrict__ b2p,
              const float* __restrict__ lnpg, const float* __restrict__ lnpb,
              const float* __restrict__ gate_p, float* __restrict__ out)
{
    extern __shared__ char lds[];
    unsigned short* o_f = (unsigned short*)lds;   // [512][41]
    float* zrT = (float*)(lds + 41984);           // [36][41]
    int b = blockIdx.x;
    int tid = threadIdx.x;

    for (int i = tid; i < DS_ * T_; i += 512) {
        int o = i / T_, s = i - o * T_;
        float v = z_pre[b * (DS_ * T_) + i];
        zrT[s * 41 + o] = fmaxf(0.f, (v - st1[o]) * st1[32 + o] * g1p[o] + b1p[o]);
    }
    __syncthreads();

    for (int i = tid; i < D_ * T_; i += 512) {
        int d = i / T_, t = i - d * T_;
        const float* zp = &zrT[t * 41 + (d >> 7) * 8];
        const float* wp = &wu[d * 8];
        f32x4 w0 = *(const f32x4*)wp;
        f32x4 w1 = *(const f32x4*)(wp + 4);
        float acc = zp[0]*w0[0] + zp[1]*w0[1] + zp[2]*w0[2] + zp[3]*w0[3]
                  + zp[4]*w1[0] + zp[5]*w1[1] + zp[6]*w1[2] + zp[7]*w1[3];
        o_f[d * 41 + t] = f2bf((acc - st2[d]) * st2[512 + d] * g2p[d] + b2p[d]);
    }
    __syncthreads();

    int w = tid >> 6, lane = tid & 63;
    float gate = gate_p[0];
    for (int t = w; t < T_; t += 8) {
        float S = 0.f, Q = 0.f;
        float v[8];
        #pragma unroll
        for (int i2 = 0; i2 < 8; ++i2) {
            float vv = bf2f(o_f[(i2 * 64 + lane) * 41 + t]);
            v[i2] = vv; S += vv; Q += vv * vv;
        }
        #pragma unroll
        for (int off = 1; off < 64; off <<= 1) { S += __shfl_xor(S, off); Q += __shfl_xor(Q, off); }
        float mu = S * (1.f / 512.f);
        float var = Q * (1.f / 512.f) - mu * mu;
        float rs = rsqrtf(var + EPS_);
        #pragma unroll
        for (int i2 = 0; i2 < 8; ++i2) {
            int d = i2 * 64 + lane;
            o_f[d * 41 + t] = f2bf(gate * ((v[i2] - mu) * rs * lnpg[d] + lnpb[d]));
        }
    }
    __syncthreads();

    float* ob = out + b * (D_ * T_);
    for (int i = tid; i < D_ * T_; i += 512) {
        int d = i / T_, t = i - d * T_;
        ob[i] = bf2f(o_f[d * 41 + t]);
    }
}

extern "C" void kernel_launch(void* const* d_in, const int* in_sizes, int n_in,
                              void* d_out, int out_size, void* d_ws, size_t ws_size,
                              hipStream_t stream)
{
    (void)in_sizes; (void)n_in; (void)out_size; (void)ws_size;
    const float* x    = (const float*)d_in[0];
    const float* y    = (const float*)d_in[1];
    const float* tok  = (const float*)d_in[2];
    const float* gate = (const float*)d_in[3];
    const float* gav  = (const float*)d_in[4];
    const float* wd   = (const float*)d_in[5];
    const float* wu   = (const float*)d_in[6];
    const float* bn1g = (const float*)d_in[7];
    const float* bn1b = (const float*)d_in[8];
    const float* bn2g = (const float*)d_in[9];
    const float* bn2b = (const float*)d_in[10];
    const float* lnbg = (const float*)d_in[11];
    const float* lnbb = (const float*)d_in[12];
    const float* lnpg = (const float*)d_in[13];
    const float* lnpb = (const float*)d_in[14];
    float* out = (float*)d_out;

    char* ws = (char*)d_ws;
    float* z_pre          = (float*)ws;                      // 4,718,592
    float* st1            = (float*)(ws + 4718592);          // 512
    unsigned short* tokbf = (unsigned short*)(ws + 4719104); // 65,536
    unsigned short* tokT  = (unsigned short*)(ws + 4784640); // 65,536
    unsigned short* wdd   = (unsigned short*)(ws + 4850176); // 32,768
    float* m4             = (float*)(ws + 4882944);          // 147,456
    float* st2            = (float*)(ws + 5030400);          // 4,096

    hipFuncSetAttribute((const void*)k1_fused, hipFuncAttributeMaxDynamicSharedMemorySize, K1_LDS);
    hipFuncSetAttribute((const void*)k5_final, hipFuncAttributeMaxDynamicSharedMemorySize, K5_LDS);

    k0_prepack<<<160, 512, 0, stream>>>(tok, wd, tokbf, tokT, wdd);
    k1_fused<<<B_, 1024, K1_LDS, stream>>>(x, y, tokbf, tokT, gav, wdd, lnbg, lnbb, z_pre);
    k3_bn1<<<DS_, 256, 0, stream>>>(z_pre, st1);
    k4m_moments<<<128, 256, 0, stream>>>(z_pre, st1, bn1g, bn1b, m4);
    k4s_bn2stats<<<1, 512, 0, stream>>>(m4, wu, st2);
    k5_final<<<B_, 512, K5_LDS, stream>>>(z_pre, st1, bn1g, bn1b, wu, st2, bn2g, bn2b,
                                          lnpg, lnpb, gate, out);
}

// Round 12
// 183.030 us; speedup vs baseline: 1.2276x; 1.2276x over previous
//
#include <hip/hip_runtime.h>

#define B_ 1024
#define D_ 512
#define T_ 36
#define NT_ 64
#define DS_ 32
#define EPS_ 1e-5f

typedef float f32x4 __attribute__((ext_vector_type(4)));
typedef __bf16 bf16x8 __attribute__((ext_vector_type(8)));
typedef unsigned short u16x8 __attribute__((ext_vector_type(8)));
typedef unsigned short u16x4 __attribute__((ext_vector_type(4)));

#define DEVI static __device__ __forceinline__
#define MFMA16 __builtin_amdgcn_mfma_f32_16x16x32_bf16

DEVI unsigned short f2bf(float f) { return __builtin_bit_cast(unsigned short, (__bf16)f); }
DEVI float bf2f(unsigned short h) { return (float)__builtin_bit_cast(__bf16, h); }

// XOR-swizzled byte offset inside a [48 rows][1024B] transposed image (T2)
DEVI unsigned swz(int row, int col) {   // col in ushort elements (0..511)
    return (unsigned)(row * 1024 + ((2 * col) ^ ((row & 7) << 4)));
}

// ---- 2-acc K=512 tile: A row from global, B from swz image ----
DEVI f32x4 tile16_gl(const unsigned short* __restrict__ Arow, const char* img, int brow, int l4)
{
    f32x4 acc0 = {0.f,0.f,0.f,0.f}, acc1 = {0.f,0.f,0.f,0.f};
    #pragma unroll
    for (int ks = 0; ks < 16; ks += 2) {
        int ka = ks * 32 + l4 * 8, kb = ka + 32;
        acc0 = MFMA16(*(const bf16x8*)(Arow + ka), *(const bf16x8*)(img + swz(brow, ka)), acc0, 0, 0, 0);
        acc1 = MFMA16(*(const bf16x8*)(Arow + kb), *(const bf16x8*)(img + swz(brow, kb)), acc1, 0, 0, 0);
    }
    return acc0 + acc1;
}

// ---- same, A also from a swizzled LDS image ----
DEVI f32x4 tile16_ll(const char* imgA, int arow, const char* imgB, int brow, int l4)
{
    f32x4 acc0 = {0.f,0.f,0.f,0.f}, acc1 = {0.f,0.f,0.f,0.f};
    #pragma unroll
    for (int ks = 0; ks < 16; ks += 2) {
        int ka = ks * 32 + l4 * 8, kb = ka + 32;
        acc0 = MFMA16(*(const bf16x8*)(imgA + swz(arow, ka)), *(const bf16x8*)(imgB + swz(brow, ka)), acc0, 0, 0, 0);
        acc1 = MFMA16(*(const bf16x8*)(imgA + swz(arow, kb)), *(const bf16x8*)(imgB + swz(brow, kb)), acc1, 0, 0, 0);
    }
    return acc0 + acc1;
}

// ---- K1 LDS layout ----
#define OFF_XST 49152    // xsT [48][1024B] swz ; h image overlay at region 0
#define OFF_SC  98304    // sc f32 [64][42] ; red overlay
#define OFF_A1  109056   // a1  u16 [64][72]
#define OFF_A1T 118272   // a1t u16 [48][72]
#define OFF_A2  125184   // a2  u16 [48][72]
#define OFF_GT  132096   // gt  u16 [48][72]
#define OFF_W   139008   // W   u16 [48][72]
#define K1_LDS  145920

// ---- K0: prepack tok bf16 [64][512], tokT bf16 [512][64], block-diag wd bf16 [32][512] ----
__global__ __launch_bounds__(512)
void k0_prepack(const float* __restrict__ tok, const float* __restrict__ wd,
                unsigned short* __restrict__ tokbf, unsigned short* __restrict__ tokT,
                unsigned short* __restrict__ wdd)
{
    int i = blockIdx.x * 512 + threadIdx.x;
    if (i < 32768) {
        tokbf[i] = f2bf(tok[i]);
    } else if (i < 65536) {
        int j = i - 32768; int d = j >> 6, t = j & 63;
        tokT[j] = f2bf(tok[t * 512 + d]);
    } else if (i < 81920) {
        int j = i - 65536; int o = j >> 9, dd = j & 511;
        wdd[j] = ((dd >> 7) == (o >> 3)) ? f2bf(wd[o * 128 + (dd & 127)]) : (unsigned short)0;
    }
}

// stage one transpose unit u (0..575) of src into image dst
DEVI void stage_unit(const float* __restrict__ src, char* __restrict__ dst, int u)
{
    int dblk = u / 9, s4 = u - dblk * 9;
    int s0 = s4 * 4;
    const float* bp = src + dblk * 8 * T_ + s0;
    u16x8 u0, u1, u2, u3;
    #pragma unroll
    for (int r = 0; r < 8; ++r) {
        f32x4 v = *(const f32x4*)(bp + r * T_);
        u0[r] = f2bf(v[0]); u1[r] = f2bf(v[1]);
        u2[r] = f2bf(v[2]); u3[r] = f2bf(v[3]);
    }
    *(u16x8*)(dst + swz(s0 + 0, dblk * 8)) = u0;
    *(u16x8*)(dst + swz(s0 + 1, dblk * 8)) = u1;
    *(u16x8*)(dst + swz(s0 + 2, dblk * 8)) = u2;
    *(u16x8*)(dst + swz(s0 + 3, dblk * 8)) = u3;
}

// =================== K1: fused attention + LN + downconv (W-algebra, phase-overlapped) ===================
__global__ __launch_bounds__(1024, 4)
void k1_fused(const float* __restrict__ x, const float* __restrict__ y,
              const unsigned short* __restrict__ tokbf, const unsigned short* __restrict__ tokT,
              const float* __restrict__ gav_p, const unsigned short* __restrict__ wdd,
              const float* __restrict__ lnbg, const float* __restrict__ lnbb,
              float* __restrict__ z_pre)
{
    extern __shared__ char lds[];
    float* sc = (float*)(lds + OFF_SC);
    unsigned short* a1  = (unsigned short*)(lds + OFF_A1);
    unsigned short* a1t = (unsigned short*)(lds + OFF_A1T);
    unsigned short* a2  = (unsigned short*)(lds + OFF_A2);
    unsigned short* gt  = (unsigned short*)(lds + OFF_GT);
    unsigned short* wb  = (unsigned short*)(lds + OFF_W);

    const int b    = blockIdx.x;
    const int tid  = threadIdx.x;
    const int lane = tid & 63;
    const int w    = tid >> 6;   // 0..15
    const int l15  = lane & 15;
    const int l4   = lane >> 4;  // 0..3

    const float* yb = y + b * (D_ * T_);
    const float* xb = x + b * (D_ * T_);

    // ---- P0: stage ysT (threads 0..575) || zero pads (threads 576..1023) ----
    if (tid < 576) {
        stage_unit(yb, lds, tid);
    } else {
        int z = tid - 576;
        unsigned* z1 = (unsigned*)(lds + 36 * 1024);
        for (int i = z; i < 3072; i += 448) z1[i] = 0u;
        unsigned* z2 = (unsigned*)(lds + OFF_XST + 36 * 1024);
        for (int i = z; i < 3072; i += 448) z2[i] = 0u;
        unsigned* z3 = (unsigned*)(lds + OFF_A1);   // a1..W contiguous: 36,864 B
        for (int i = z; i < 9216; i += 448) z3[i] = 0u;
    }
    __syncthreads();

    // ---- P1a: G1 (S1 = tok@y, 12 tiles, waves 0..11) || stage xsT (waves 12..15) ----
    if (w < 12) {
        int mt = w / 3, nt = w % 3;
        int trow = mt * 16 + l15, srow = nt * 16 + l15;
        f32x4 acc = tile16_gl(tokbf + trow * 512, lds, srow, l4);
        if (srow < T_) {
            #pragma unroll
            for (int j = 0; j < 4; ++j)
                sc[(mt * 16 + l4 * 4 + j) * 42 + srow] = acc[j];
        }
    } else {
        for (int u = tid - 768; u < 576; u += 256)
            stage_unit(xb, lds + OFF_XST, u);
    }
    __syncthreads();

    // ---- P1b: Gram (waves 0..8) || sm1 (waves 12..15, 4-lane groups) ; y-prefetch (all) ----
    if (w < 9) {
        int mt = w / 3, nt = w % 3;
        int arow = mt * 16 + l15, brow = nt * 16 + l15;
        f32x4 acc = tile16_ll(lds + OFF_XST, arow, lds, brow, l4);
        #pragma unroll
        for (int j = 0; j < 4; ++j) {
            int gr = mt * 16 + l4 * 4 + j;
            if (gr < T_) gt[gr * 72 + brow] = f2bf(acc[j]);
        }
    } else if (w >= 12) {
        int t = (tid - 768) >> 2, l2 = tid & 3;
        const float* scp = sc + t * 42 + l2 * 9;
        float v[9];
        float m = -1e30f;
        #pragma unroll
        for (int j = 0; j < 9; ++j) { v[j] = scp[j]; m = fmaxf(m, v[j]); }
        m = fmaxf(m, __shfl_xor(m, 1));
        m = fmaxf(m, __shfl_xor(m, 2));
        float e[9], ssum = 0.f;
        #pragma unroll
        for (int j = 0; j < 9; ++j) { e[j] = __expf(v[j] - m); ssum += e[j]; }
        ssum += __shfl_xor(ssum, 1);
        ssum += __shfl_xor(ssum, 2);
        float inv = 1.f / ssum;
        #pragma unroll
        for (int j = 0; j < 9; ++j) {
            unsigned short h = f2bf(e[j] * inv);
            int s = l2 * 9 + j;
            a1[t * 72 + s] = h;
            a1t[s * 72 + t] = h;
        }
    }
    // prefetch y rows for P6 (held in registers across P3/P5)
    f32x4 py0[2], py1[2], py2[2];
    #pragma unroll
    for (int mi = 0; mi < 2; ++mi) {
        const float* yrow = yb + ((2 * w + mi) * 16 + l15) * T_;
        py0[mi] = *(const f32x4*)(yrow + l4 * 8);
        py1[mi] = *(const f32x4*)(yrow + l4 * 8 + 4);
        if (l4 == 0) py2[mi] = *(const f32x4*)(yrow + 32);
        else         py2[mi] = (f32x4){0.f, 0.f, 0.f, 0.f};
    }
    __syncthreads();

    // ---- P3: S2[t][s] = tok@x (K=512) + a1@gt^T (K=36 pad 64); 12 tiles ----
    if (w < 12) {
        int mt = w / 3, nt = w % 3;
        int trow = mt * 16 + l15, srow = nt * 16 + l15;
        bf16x8 sa0 = *(const bf16x8*)(a1 + trow * 72 + l4 * 8);
        bf16x8 sa1 = *(const bf16x8*)(a1 + trow * 72 + 32 + l4 * 8);
        bf16x8 sb0 = *(const bf16x8*)(gt + srow * 72 + l4 * 8);
        bf16x8 sb1 = *(const bf16x8*)(gt + srow * 72 + 32 + l4 * 8);
        f32x4 acc = tile16_gl(tokbf + trow * 512, lds + OFF_XST, srow, l4);
        acc = MFMA16(sa0, sb0, acc, 0, 0, 0);
        acc = MFMA16(sa1, sb1, acc, 0, 0, 0);
        if (srow < T_) {
            #pragma unroll
            for (int j = 0; j < 4; ++j)
                sc[(mt * 16 + l4 * 4 + j) * 42 + srow] = acc[j];
        }
    }
    __syncthreads();

    // ---- sm2: softmax over t per s -> a2 [s][t] ----
    if (tid < 768) {
        int s = tid >> 4, l16 = tid & 15;
        if (s < T_) {
            float v0 = sc[(l16) * 42 + s];
            float v1 = sc[(l16 + 16) * 42 + s];
            float v2 = sc[(l16 + 32) * 42 + s];
            float v3 = sc[(l16 + 48) * 42 + s];
            float m = fmaxf(fmaxf(v0, v1), fmaxf(v2, v3));
            #pragma unroll
            for (int off = 1; off < 16; off <<= 1) m = fmaxf(m, __shfl_xor(m, off));
            float e0 = __expf(v0 - m), e1 = __expf(v1 - m), e2 = __expf(v2 - m), e3 = __expf(v3 - m);
            float ssum = e0 + e1 + e2 + e3;
            #pragma unroll
            for (int off = 1; off < 16; off <<= 1) ssum += __shfl_xor(ssum, off);
            float inv = 1.f / ssum;
            a2[s * 72 + l16]      = f2bf(e0 * inv);
            a2[s * 72 + l16 + 16] = f2bf(e1 * inv);
            a2[s * 72 + l16 + 32] = f2bf(e2 * inv);
            a2[s * 72 + l16 + 48] = f2bf(e3 * inv);
        }
    }
    __syncthreads();

    // ---- P5: W[s2][s1] = a2 @ a1t^T (K=t=64, 9 tiles) ----
    if (w < 9) {
        int mt = w / 3, nt = w % 3;
        f32x4 acc = {0.f, 0.f, 0.f, 0.f};
        #pragma unroll
        for (int ks = 0; ks < 2; ++ks) {
            int k0 = ks * 32 + l4 * 8;
            acc = MFMA16(*(const bf16x8*)(a2 + (mt * 16 + l15) * 72 + k0),
                         *(const bf16x8*)(a1t + (nt * 16 + l15) * 72 + k0), acc, 0, 0, 0);
        }
        #pragma unroll
        for (int j = 0; j < 4; ++j)
            wb[(mt * 16 + l4 * 4 + j) * 72 + nt * 16 + l15] = f2bf(acc[j]);
    }
    __syncthreads();

    // ---- P6: xresT[d][s] = tokT@a2^T + y@W^T ; xc ; LN -> h image (region 0) ----
    {
        const float gav = gav_p[0];
        f32x4 acc[2][3];
        #pragma unroll
        for (int mi = 0; mi < 2; ++mi)
            #pragma unroll
            for (int n = 0; n < 3; ++n) acc[mi][n] = (f32x4){0.f, 0.f, 0.f, 0.f};

        bf16x8 aT[2][2], aY[2][2];
        #pragma unroll
        for (int mi = 0; mi < 2; ++mi) {
            int d = (2 * w + mi) * 16 + l15;
            aT[mi][0] = *(const bf16x8*)(tokT + d * 64 + l4 * 8);
            aT[mi][1] = *(const bf16x8*)(tokT + d * 64 + 32 + l4 * 8);
            bf16x8 t0, t1;
            #pragma unroll
            for (int j = 0; j < 4; ++j) {
                t0[j] = (__bf16)py0[mi][j]; t0[4 + j] = (__bf16)py1[mi][j];
                t1[j] = (__bf16)py2[mi][j]; t1[4 + j] = (__bf16)0.f;
            }
            aY[mi][0] = t0; aY[mi][1] = t1;
        }
        #pragma unroll
        for (int n = 0; n < 3; ++n) {
            int srow = n * 16 + l15;
            bf16x8 b20 = *(const bf16x8*)(a2 + srow * 72 + l4 * 8);
            bf16x8 b21 = *(const bf16x8*)(a2 + srow * 72 + 32 + l4 * 8);
            bf16x8 bw0 = *(const bf16x8*)(wb + srow * 72 + l4 * 8);
            bf16x8 bw1 = *(const bf16x8*)(wb + srow * 72 + 32 + l4 * 8);
            #pragma unroll
            for (int mi = 0; mi < 2; ++mi) {
                acc[mi][n] = MFMA16(aT[mi][0], b20, acc[mi][n], 0, 0, 0);
                acc[mi][n] = MFMA16(aT[mi][1], b21, acc[mi][n], 0, 0, 0);
                acc[mi][n] = MFMA16(aY[mi][0], bw0, acc[mi][n], 0, 0, 0);
                acc[mi][n] = MFMA16(aY[mi][1], bw1, acc[mi][n], 0, 0, 0);
            }
        }

        // xc = xs + gav*x_res ; per-s LN partials (u16x4 xc reads)
        float* red = sc;   // overlays dead sc
        float rs_[3] = {0.f, 0.f, 0.f}, rq_[3] = {0.f, 0.f, 0.f};
        #pragma unroll
        for (int mi = 0; mi < 2; ++mi) {
            int dcol = (2 * w + mi) * 16 + l4 * 4;
            #pragma unroll
            for (int n = 0; n < 3; ++n) {
                int s = n * 16 + l15;
                if (s < T_) {
                    u16x4 xv = *(const u16x4*)(lds + OFF_XST + swz(s, dcol));
                    #pragma unroll
                    for (int j = 0; j < 4; ++j) {
                        float v = bf2f(xv[j]) + gav * acc[mi][n][j];
                        acc[mi][n][j] = v;
                        rs_[n] += v; rq_[n] += v * v;
                    }
                }
            }
        }
        #pragma unroll
        for (int n = 0; n < 3; ++n) {
            rs_[n] += __shfl_xor(rs_[n], 16); rq_[n] += __shfl_xor(rq_[n], 16);
            rs_[n] += __shfl_xor(rs_[n], 32); rq_[n] += __shfl_xor(rq_[n], 32);
        }
        if (l4 == 0) {
            #pragma unroll
            for (int n = 0; n < 3; ++n) {
                int s = n * 16 + l15;
                if (s < T_) { red[s * 16 + w] = rs_[n]; red[768 + s * 16 + w] = rq_[n]; }
            }
        }
        __syncthreads();
        if (tid < T_) {
            int s = tid; float S = 0.f, Q = 0.f;
            #pragma unroll
            for (int q = 0; q < 16; ++q) { S += red[s * 16 + q]; Q += red[768 + s * 16 + q]; }
            float mu = S * (1.f / 512.f);
            float var = Q * (1.f / 512.f) - mu * mu;
            red[1536 + s] = mu; red[1584 + s] = rsqrtf(var + EPS_);
        }
        __syncthreads();

        // h (LN output) -> region 0 image (ysT dead); u16x4 writes
        #pragma unroll
        for (int mi = 0; mi < 2; ++mi) {
            int dcol = (2 * w + mi) * 16 + l4 * 4;
            f32x4 gv  = *(const f32x4*)(lnbg + dcol);
            f32x4 bv2 = *(const f32x4*)(lnbb + dcol);
            #pragma unroll
            for (int n = 0; n < 3; ++n) {
                int s = n * 16 + l15;
                if (s < T_) {
                    float mu = red[1536 + s], rsg = red[1584 + s];
                    u16x4 hv;
                    #pragma unroll
                    for (int j = 0; j < 4; ++j)
                        hv[j] = f2bf((acc[mi][n][j] - mu) * rsg * gv[j] + bv2[j]);
                    *(u16x4*)(lds + swz(s, dcol)) = hv;
                }
            }
        }
    }
    __syncthreads();

    // ---- P7: grouped down conv via MFMA: z[o][s] = wdd(blockdiag) @ h ----
    if (w < 6) {
        int mt = w / 3, nt = w % 3;
        int orow = mt * 16 + l15, srow = nt * 16 + l15;
        f32x4 acc = tile16_gl(wdd + orow * 512, lds, srow, l4);
        if (srow < T_) {
            #pragma unroll
            for (int j = 0; j < 4; ++j)
                z_pre[b * (DS_ * T_) + (mt * 16 + l4 * 4 + j) * T_ + srow] = acc[j];
        }
    }
}

// ---- K3: bn1 stats, two-level (512 blocks + 1 block) ----
__global__ __launch_bounds__(256)
void k3a_bn1part(const float* __restrict__ z_pre, float* __restrict__ p3)
{
    __shared__ float rbuf[4][2];
    int blk = blockIdx.x;
    int o = blk & 31, sl = blk >> 5;
    int tid = threadIdx.x;
    float S = 0.f, Q = 0.f;
    for (int i = tid; i < 64 * T_; i += 256) {
        int bb = sl * 64 + i / T_, t = i - (i / T_) * T_;
        float v = z_pre[bb * (DS_ * T_) + o * T_ + t];
        S += v; Q += v * v;
    }
    #pragma unroll
    for (int off = 1; off < 64; off <<= 1) { S += __shfl_xor(S, off); Q += __shfl_xor(Q, off); }
    int ww = tid >> 6;
    if ((tid & 63) == 0) { rbuf[ww][0] = S; rbuf[ww][1] = Q; }
    __syncthreads();
    if (tid == 0) {
        float s2 = 0.f, q2 = 0.f;
        for (int i = 0; i < 4; ++i) { s2 += rbuf[i][0]; q2 += rbuf[i][1]; }
        p3[blk * 2] = s2; p3[blk * 2 + 1] = q2;
    }
}

__global__ __launch_bounds__(64)
void k3b_bn1stats(const float* __restrict__ p3, float* __restrict__ st1)
{
    int o = threadIdx.x;
    if (o < 32) {
        float S = 0.f, Q = 0.f;
        for (int sl = 0; sl < 16; ++sl) {
            S += p3[((sl << 5) | o) * 2];
            Q += p3[((sl << 5) | o) * 2 + 1];
        }
        float mu = S / 36864.f;
        float var = Q / 36864.f - mu * mu;
        st1[o] = mu; st1[32 + o] = rsqrtf(var + EPS_);
    }
}

// ---- K4M: per-group 8x8 second-moment partials of zr = relu(bn1(z)) ----
__global__ __launch_bounds__(256)
void k4m_moments(const float* __restrict__ z_pre, const float* __restrict__ st1,
                 const float* __restrict__ g1p, const float* __restrict__ b1p,
                 float* __restrict__ m4)
{
    __shared__ float zr[32][40];
    int blk = blockIdx.x, tid = threadIdx.x;
    int c2 = tid & 7, c1 = (tid >> 3) & 7, g = tid >> 6;
    int ch1 = g * 8 + c1, ch2 = g * 8 + c2;
    float acc = 0.f, asum = 0.f;
    for (int bi = 0; bi < 8; ++bi) {
        int b = blk * 8 + bi;
        __syncthreads();
        for (int i = tid; i < DS_ * T_; i += 256) {
            int o = i / T_, t = i - o * T_;
            float v = z_pre[b * (DS_ * T_) + i];
            zr[o][t] = fmaxf(0.f, (v - st1[o]) * st1[32 + o] * g1p[o] + b1p[o]);
        }
        __syncthreads();
        for (int t = 0; t < T_; ++t) {
            float a = zr[ch1][t], b2 = zr[ch2][t];
            acc += a * b2;
            asum += a;
        }
    }
    m4[blk * 288 + tid] = acc;
    if (c1 == c2) m4[blk * 288 + 256 + g * 8 + c1] = asum;
}

// ---- K4S: reduce moments -> bn2 stats via E[o^2] = w^T M w ----
__global__ __launch_bounds__(512)
void k4s_bn2stats(const float* __restrict__ m4, const float* __restrict__ wu,
                  float* __restrict__ st2)
{
    __shared__ float M2[256], mz[32];
    int tid = threadIdx.x;
    if (tid < 256) {
        float S = 0.f;
        for (int k = 0; k < 128; ++k) S += m4[k * 288 + tid];
        M2[tid] = S * (1.f / 36864.f);
    } else if (tid < 288) {
        int j = tid - 256;
        float S = 0.f;
        for (int k = 0; k < 128; ++k) S += m4[k * 288 + 256 + j];
        mz[j] = S * (1.f / 36864.f);
    }
    __syncthreads();
    int d = tid, g = d >> 7;
    float wr[8];
    #pragma unroll
    for (int c = 0; c < 8; ++c) wr[c] = wu[d * 8 + c];
    float mu2 = 0.f;
    #pragma unroll
    for (int c = 0; c < 8; ++c) mu2 += wr[c] * mz[g * 8 + c];
    float e2 = 0.f;
    #pragma unroll
    for (int c = 0; c < 8; ++c)
        #pragma unroll
        for (int c2 = 0; c2 < 8; ++c2)
            e2 += wr[c] * wr[c2] * M2[g * 64 + c * 8 + c2];
    st2[d] = mu2;
    st2[512 + d] = rsqrtf(e2 - mu2 * mu2 + EPS_);
}

// ---- K5: up conv + bn2 + LN(lnp) + gate -> out ----
#define K5_LDS 47888
__global__ __launch_bounds__(512, 6)
void k5_final(const float* __restrict__ z_pre, const float* __restrict__ st1,
              const float* __restrict__ g1p, const float* __restrict__ b1p,
              const float* __restrict__ wu, const float* __restrict__ st2,
              const float* __restrict__ g2p, const float* __restrict__ b2p,
              const float* __restrict__ lnpg, const float* __restrict__ lnpb,
              const float* __restrict__ gate_p, float* __restrict__ out)
{
    extern __shared__ char lds[];
    unsigned short* o_f = (unsigned short*)lds;   // [512][41]
    float* zrT = (float*)(lds + 41984);           // [36][41]
    int b = blockIdx.x;
    int tid = threadIdx.x;

    for (int i = tid; i < DS_ * T_; i += 512) {
        int o = i / T_, s = i - o * T_;
        float v = z_pre[b * (DS_ * T_) + i];
        zrT[s * 41 + o] = fmaxf(0.f, (v - st1[o]) * st1[32 + o] * g1p[o] + b1p[o]);
    }
    __syncthreads();

    for (int i = tid; i < D_ * T_; i += 512) {
        int d = i / T_, t = i - d * T_;
        const float* zp = &zrT[t * 41 + (d >> 7) * 8];
        const float* wp = &wu[d * 8];
        f32x4 w0 = *(const f32x4*)wp;
        f32x4 w1 = *(const f32x4*)(wp + 4);
        float acc = zp[0]*w0[0] + zp[1]*w0[1] + zp[2]*w0[2] + zp[3]*w0[3]
                  + zp[4]*w1[0] + zp[5]*w1[1] + zp[6]*w1[2] + zp[7]*w1[3];
        o_f[d * 41 + t] = f2bf((acc - st2[d]) * st2[512 + d] * g2p[d] + b2p[d]);
    }
    __syncthreads();

    int w = tid >> 6, lane = tid & 63;
    float gate = gate_p[0];
    for (int t = w; t < T_; t += 8) {
        float S = 0.f, Q = 0.f;
        float v[8];
        #pragma unroll
        for (int i2 = 0; i2 < 8; ++i2) {
            float vv = bf2f(o_f[(i2 * 64 + lane) * 41 + t]);
            v[i2] = vv; S += vv; Q += vv * vv;
        }
        #pragma unroll
        for (int off = 1; off < 64; off <<= 1) { S += __shfl_xor(S, off); Q += __shfl_xor(Q, off); }
        float mu = S * (1.f / 512.f);
        float var = Q * (1.f / 512.f) - mu * mu;
        float rs = rsqrtf(var + EPS_);
        #pragma unroll
        for (int i2 = 0; i2 < 8; ++i2) {
            int d = i2 * 64 + lane;
            o_f[d * 41 + t] = f2bf(gate * ((v[i2] - mu) * rs * lnpg[d] + lnpb[d]));
        }
    }
    __syncthreads();

    float* ob = out + b * (D_ * T_);
    for (int i = tid; i < D_ * T_; i += 512) {
        int d = i / T_, t = i - d * T_;
        ob[i] = bf2f(o_f[d * 41 + t]);
    }
}

extern "C" void kernel_launch(void* const* d_in, const int* in_sizes, int n_in,
                              void* d_out, int out_size, void* d_ws, size_t ws_size,
                              hipStream_t stream)
{
    (void)in_sizes; (void)n_in; (void)out_size; (void)ws_size;
    const float* x    = (const float*)d_in[0];
    const float* y    = (const float*)d_in[1];
    const float* tok  = (const float*)d_in[2];
    const float* gate = (const float*)d_in[3];
    const float* gav  = (const float*)d_in[4];
    const float* wd   = (const float*)d_in[5];
    const float* wu   = (const float*)d_in[6];
    const float* bn1g = (const float*)d_in[7];
    const float* bn1b = (const float*)d_in[8];
    const float* bn2g = (const float*)d_in[9];
    const float* bn2b = (const float*)d_in[10];
    const float* lnbg = (const float*)d_in[11];
    const float* lnbb = (const float*)d_in[12];
    const float* lnpg = (const float*)d_in[13];
    const float* lnpb = (const float*)d_in[14];
    float* out = (float*)d_out;

    char* ws = (char*)d_ws;
    float* z_pre          = (float*)ws;                      // 4,718,592
    float* st1            = (float*)(ws + 4718592);          // 512
    unsigned short* tokbf = (unsigned short*)(ws + 4719104); // 65,536
    unsigned short* tokT  = (unsigned short*)(ws + 4784640); // 65,536
    unsigned short* wdd   = (unsigned short*)(ws + 4850176); // 32,768
    float* p3             = (float*)(ws + 4882944);          // 4,096
    float* m4             = (float*)(ws + 4887040);          // 147,456
    float* st2            = (float*)(ws + 5034496);          // 4,096

    hipFuncSetAttribute((const void*)k1_fused, hipFuncAttributeMaxDynamicSharedMemorySize, K1_LDS);
    hipFuncSetAttribute((const void*)k5_final, hipFuncAttributeMaxDynamicSharedMemorySize, K5_LDS);

    k0_prepack<<<160, 512, 0, stream>>>(tok, wd, tokbf, tokT, wdd);
    k1_fused<<<B_, 1024, K1_LDS, stream>>>(x, y, tokbf, tokT, gav, wdd, lnbg, lnbb, z_pre);
    k3a_bn1part<<<512, 256, 0, stream>>>(z_pre, p3);
    k3b_bn1stats<<<1, 64, 0, stream>>>(p3, st1);
    k4m_moments<<<128, 256, 0, stream>>>(z_pre, st1, bn1g, bn1b, m4);
    k4s_bn2stats<<<1, 512, 0, stream>>>(m4, wu, st2);
    k5_final<<<B_, 512, K5_LDS, stream>>>(z_pre, st1, bn1g, bn1b, wu, st2, bn2g, bn2b,
                                          lnpg, lnpb, gate, out);
}